// Round 7
// baseline (10377.270 us; speedup 1.0000x reference)
//
#include <hip/hip_runtime.h>
#include <hip/hip_bf16.h>

// Problem constants (reference: t1_t0=1, TOL=0.05 -> 20 SSP-RK3 steps)
#define MB     32
#define NCH    4
#define LL     2048
#define HID    64
#define KSZ    5
#define GG     10
#define RI     (LL - 2*GG)   // 2028
#define TPOS   128
#define NTILES 16
#define THR    256
#define NSTEPS 20
#define HSTEP  0.05f

__device__ __forceinline__ int pmap(int q) {
  // bdry read map: ghost -> interior source (period RI)
  if (q < GG) return q + RI;
  if (q >= LL - GG) return q - RI;
  return q;
}

// ======================= proven round-2 per-stage kernel =======================
template<bool MAP, bool SCATTER>
__global__ __launch_bounds__(THR, 2)
void stage_kernel(const float* __restrict__ z, const float* __restrict__ cin,
                  float* __restrict__ outp,
                  const float* __restrict__ W1g, const float* __restrict__ b1g,
                  const float* __restrict__ W2g, const float* __restrict__ b2g,
                  float ca, float cb, float cc_)
{
  __shared__ float in_s[NCH][TPOS + 8];
  __shared__ __align__(16) float th_s[TPOS + 4][HID];
  __shared__ __align__(16) float w2s[NCH][KSZ][HID];
  __shared__ float b2s[NCH];

  const int t    = threadIdx.x;
  const int tile = blockIdx.x;
  const int mi   = blockIdx.y;
  const int p0 = GG + tile * TPOS;
  const int validT = min(TPOS, (LL - GG) - p0);

  for (int i = t; i < NCH * KSZ * HID; i += THR) {
    int co = i / (KSZ * HID); int rem = i - co * (KSZ * HID);
    int k = rem / HID; int c2 = rem - k * HID;
    w2s[co][k][c2] = W2g[(co * HID + c2) * KSZ + k];
  }
  if (t < NCH) b2s[t] = b2g[t];
  const int c = t & 63;
  float w1r[NCH * KSZ];
  #pragma unroll
  for (int i = 0; i < NCH * KSZ; ++i) w1r[i] = W1g[c * (NCH * KSZ) + i];
  const float b1r = b1g[c];

  const float* zb   = z   + mi * (NCH * LL);
  const float* cinb = cin + mi * (NCH * LL);
  float*       outb = outp + mi * (NCH * LL);

  const int LOADN = validT + 8;
  for (int i = t; i < NCH * (TPOS + 8); i += THR) {
    int ci = i / (TPOS + 8);
    int j  = i - ci * (TPOS + 8);
    if (j < LOADN) {
      int q  = p0 - 4 + j;
      int qq = MAP ? pmap(q) : q;
      in_s[ci][j] = cinb[ci * LL + qq];
    }
  }
  __syncthreads();

  {
    const int pg = t >> 6;
    const int THN = validT + 4;
    const int j0  = pg * 35;
    const int j1  = min(THN, j0 + 35);
    float zw[NCH][KSZ];
    #pragma unroll
    for (int d = 0; d < 4; ++d) {
      #pragma unroll
      for (int ci = 0; ci < NCH; ++ci)
        zw[ci][d] = in_s[ci][j0 + d];
    }
    for (int jb = j0; jb < j1; jb += 5) {
      #pragma unroll
      for (int u = 0; u < 5; ++u) {
        int j = jb + u;
        if (j < j1) {
          #pragma unroll
          for (int ci = 0; ci < NCH; ++ci)
            zw[ci][(u + 4) % 5] = in_s[ci][j + 4];
          float acc = b1r;
          #pragma unroll
          for (int ci = 0; ci < NCH; ++ci) {
            #pragma unroll
            for (int k = 0; k < KSZ; ++k)
              acc = fmaf(w1r[ci * KSZ + k], zw[ci][(u + k) % 5], acc);
          }
          float e  = __expf(2.0f * acc);
          float th = 1.0f - 2.0f * __frcp_rn(e + 1.0f);
          th_s[j][(((c >> 2) ^ (j & 15)) << 2) | (c & 3)] = th;
        }
      }
    }
  }
  __syncthreads();

  {
    const int x   = t >> 1;
    const int cop = t & 1;
    if (x < validT) {
      const int co0 = cop * 2, co1 = co0 + 1;
      float a0 = b2s[co0], a1 = b2s[co1];
      const float4* w2v0 = (const float4*)&w2s[co0][0][0];
      const float4* w2v1 = (const float4*)&w2s[co1][0][0];
      #pragma unroll
      for (int k = 0; k < KSZ; ++k) {
        const int row = x + k;
        const float4* thv = (const float4*)&th_s[row][0];
        const int rs = row & 15;
        #pragma unroll
        for (int ccn = 0; ccn < 16; ++ccn) {
          float4 tv = thv[ccn ^ rs];
          float4 wa = w2v0[k * 16 + ccn];
          float4 wb = w2v1[k * 16 + ccn];
          a0 = fmaf(tv.x, wa.x, a0); a0 = fmaf(tv.y, wa.y, a0);
          a0 = fmaf(tv.z, wa.z, a0); a0 = fmaf(tv.w, wa.w, a0);
          a1 = fmaf(tv.x, wb.x, a1); a1 = fmaf(tv.y, wb.y, a1);
          a1 = fmaf(tv.z, wb.z, a1); a1 = fmaf(tv.w, wb.w, a1);
        }
      }
      const int p = p0 + x;
      float v0 = ca * zb[co0 * LL + p] + cb * cinb[co0 * LL + p] + cc_ * a0;
      float v1 = ca * zb[co1 * LL + p] + cb * cinb[co1 * LL + p] + cc_ * a1;
      outb[co0 * LL + p] = v0;
      outb[co1 * LL + p] = v1;
      if (SCATTER) {
        if (p >= LL - 2 * GG && p < LL - GG) {
          outb[co0 * LL + p - RI] = v0;
          outb[co1 * LL + p - RI] = v1;
        }
        if (p >= GG && p < 2 * GG) {
          outb[co0 * LL + p + RI] = v0;
          outb[co1 * LL + p + RI] = v1;
        }
      }
    }
  }
}

// ======================= fused full-step kernel (steps >= 2) ====================
// conv1: th_s[j] = tanh(conv1 @ window in_sv[j..j+4]) for j in wave's strip.
// All 64 lanes of a wave read the SAME in_sv address (lane = hidden channel)
// -> LDS broadcast, conflict-free. No carried window state (spill-proof).
__device__ __forceinline__ void run_conv1(const float4* __restrict__ in_sv,
                                          float (*th_s)[HID],
                                          int R, int t,
                                          const float* __restrict__ w1r, float b1r)
{
  const int c  = t & 63;
  const int pg = t >> 6;
  const int RP = (R + 3) >> 2;
  const int j0 = pg * RP;
  const int j1 = min(R, j0 + RP);
  for (int j = j0; j < j1; ++j) {
    float acc = b1r;
    #pragma unroll
    for (int k = 0; k < KSZ; ++k) {
      float4 pk = in_sv[j + k];
      acc = fmaf(w1r[0 * KSZ + k], pk.x, acc);
      acc = fmaf(w1r[1 * KSZ + k], pk.y, acc);
      acc = fmaf(w1r[2 * KSZ + k], pk.z, acc);
      acc = fmaf(w1r[3 * KSZ + k], pk.w, acc);
    }
    float e  = __expf(2.0f * acc);
    float th = 1.0f - 2.0f * __frcp_rn(e + 1.0f);
    th_s[j][(((c >> 2) ^ (j & 15)) << 2) | (c & 3)] = th;
  }
}

// conv2 + combine. z-term: in_sv[x+zoff]; cin-term: cin_sv[x+4] (or none).
// Output: LDS float4 (outv) or global LINE layout with ghost scatter (outg).
template<bool SCAT>
__device__ __forceinline__ void run_conv2(const float (*th_s)[HID],
                                          const float4* __restrict__ in_sv, int zoff,
                                          const float4* __restrict__ cin_sv,
                                          float ca, float cb, float cc_,
                                          int No, int t,
                                          const float (*w2s)[KSZ][HID],
                                          const float* __restrict__ b2s,
                                          float4* __restrict__ outv,
                                          float* __restrict__ outb, int p0line)
{
  const int cop = t & 1;
  const int co0 = cop * 2, co1 = co0 + 1;
  const float4* w2v0 = (const float4*)&w2s[co0][0][0];
  const float4* w2v1 = (const float4*)&w2s[co1][0][0];
  for (int x = t >> 1; x < No; x += 128) {
    float a0 = b2s[co0], a1 = b2s[co1];
    #pragma unroll
    for (int k = 0; k < KSZ; ++k) {
      const int row = x + k;
      const float4* thv = (const float4*)&th_s[row][0];
      const int rs = row & 15;
      #pragma unroll
      for (int ccn = 0; ccn < 16; ++ccn) {
        float4 tv = thv[ccn ^ rs];
        float4 wa = w2v0[k * 16 + ccn];
        float4 wb = w2v1[k * 16 + ccn];
        a0 = fmaf(tv.x, wa.x, a0); a0 = fmaf(tv.y, wa.y, a0);
        a0 = fmaf(tv.z, wa.z, a0); a0 = fmaf(tv.w, wa.w, a0);
        a1 = fmaf(tv.x, wb.x, a1); a1 = fmaf(tv.y, wb.y, a1);
        a1 = fmaf(tv.z, wb.z, a1); a1 = fmaf(tv.w, wb.w, a1);
      }
    }
    const float* zp = (const float*)&in_sv[x + zoff];
    float c0v = 0.0f, c1v = 0.0f;
    if (cin_sv) {
      const float* cp = (const float*)&cin_sv[x + 4];
      c0v = cp[co0]; c1v = cp[co1];
    }
    float v0 = ca * zp[co0] + cb * c0v + cc_ * a0;
    float v1 = ca * zp[co1] + cb * c1v + cc_ * a1;
    if (outv) {
      float* op = (float*)&outv[x];
      op[co0] = v0; op[co1] = v1;
    } else {
      const int p = p0line + x;
      outb[co0 * LL + p] = v0;
      outb[co1 * LL + p] = v1;
      if (SCAT) {
        if (p >= LL - 2 * GG && p < LL - GG) {
          outb[co0 * LL + p - RI] = v0;
          outb[co1 * LL + p - RI] = v1;
        }
        if (p >= GG && p < 2 * GG) {
          outb[co0 * LL + p + RI] = v0;
          outb[co1 * LL + p + RI] = v1;
        }
      }
    }
  }
}

// One full SSP-RK3 step (z has bdry-consistent state; ring-wrap == bdry).
__global__ __launch_bounds__(THR, 2)
void fused_step(const float* __restrict__ zin, float* __restrict__ zout,
                const float* __restrict__ W1g, const float* __restrict__ b1g,
                const float* __restrict__ W2g, const float* __restrict__ b2g)
{
  __shared__ float4 in_sv[TPOS + 24];                   // z ext [-12, T+12)
  __shared__ __align__(16) float th_s[TPOS + 20][HID];
  __shared__ float4 u1_sv[TPOS + 16];                   // u1 ext [-8, T+8)
  __shared__ float4 u2_sv[TPOS + 8];                    // u2 ext [-4, T+4)
  __shared__ __align__(16) float w2s[NCH][KSZ][HID];
  __shared__ float b2s[NCH];

  const int t    = threadIdx.x;
  const int tile = blockIdx.x;
  const int mi   = blockIdx.y;
  const int r0   = tile * TPOS;                         // ring coord of tile start
  const int validT = min(TPOS, RI - r0);

  for (int i = t; i < NCH * KSZ * HID; i += THR) {
    int co = i / (KSZ * HID); int rem = i - co * (KSZ * HID);
    int k = rem / HID; int c2 = rem - k * HID;
    w2s[co][k][c2] = W2g[(co * HID + c2) * KSZ + k];
  }
  if (t < NCH) b2s[t] = b2g[t];
  const int c = t & 63;
  float w1r[NCH * KSZ];
  #pragma unroll
  for (int i = 0; i < NCH * KSZ; ++i) w1r[i] = W1g[c * (NCH * KSZ) + i];
  const float b1r = b1g[c];

  const float h = HSTEP;
  const float* zb = zin  + (size_t)mi * NCH * LL;
  float*     outb = zout + (size_t)mi * NCH * LL;

  // load z ext tile (interior reads only; ring wrap == bdry for steps >= 2)
  for (int j = t; j < validT + 24; j += THR) {
    int q = r0 + j - 12; if (q < 0) q += RI; if (q >= RI) q -= RI;
    int lp = q + GG;
    in_sv[j] = make_float4(zb[0 * LL + lp], zb[1 * LL + lp],
                           zb[2 * LL + lp], zb[3 * LL + lp]);
  }
  __syncthreads();

  // stage 1: u1 = z + h f(z) on ext [-8, T+8)
  run_conv1(in_sv, th_s, validT + 20, t, w1r, b1r);
  __syncthreads();
  run_conv2<false>(th_s, in_sv, 4, nullptr, 1.0f, 0.0f, h,
                   validT + 16, t, w2s, b2s, u1_sv, nullptr, 0);
  __syncthreads();
  // stage 2: u2 = 0.75 z + 0.25 u1 + 0.25 h f(u1) on ext [-4, T+4)
  run_conv1(u1_sv, th_s, validT + 12, t, w1r, b1r);
  __syncthreads();
  run_conv2<false>(th_s, in_sv, 8, u1_sv, 0.75f, 0.25f, 0.25f * h,
                   validT + 8, t, w2s, b2s, u2_sv, nullptr, 0);
  __syncthreads();
  // stage 3: z' = z/3 + 2/3 u2 + (2h/3) f(u2) on [0, T) -> global line + ghosts
  run_conv1(u2_sv, th_s, validT + 4, t, w1r, b1r);
  __syncthreads();
  run_conv2<true>(th_s, in_sv, 12, u2_sv, 1.0f / 3.0f, 2.0f / 3.0f, 2.0f * h / 3.0f,
                  validT, t, w2s, b2s, nullptr, outb, r0 + GG);
}

extern "C" void kernel_launch(void* const* d_in, const int* in_sizes, int n_in,
                              void* d_out, int out_size, void* d_ws, size_t ws_size,
                              hipStream_t stream) {
  const float* z0 = (const float*)d_in[0];
  const float* W1 = (const float*)d_in[1];
  const float* b1 = (const float*)d_in[2];
  const float* W2 = (const float*)d_in[3];
  const float* b2 = (const float*)d_in[4];
  float* out = (float*)d_out;

  const size_t ELEMS = (size_t)MB * NCH * LL;
  float* zA  = (float*)d_ws;
  float* zB  = zA + ELEMS;
  float* u1p = zB + ELEMS;
  float* u2p = u1p + ELEMS;

  const float h = HSTEP;
  dim3 grid(NTILES, MB);
  dim3 block(THR);

  // ---- step 1: per-stage (z0's raw ghosts are semantically meaningful) ----
  stage_kernel<false, false><<<grid, block, 0, stream>>>(
      z0, z0, u1p, W1, b1, W2, b2, 1.0f, 0.0f, h);
  stage_kernel<true, false><<<grid, block, 0, stream>>>(
      z0, u1p, u2p, W1, b1, W2, b2, 0.75f, 0.25f, 0.25f * h);
  stage_kernel<true, true><<<grid, block, 0, stream>>>(
      z0, u2p, zA, W1, b1, W2, b2, 1.0f / 3.0f, 2.0f / 3.0f, 2.0f * h / 3.0f);

  // ---- steps 2..20: one fused launch per step ----
  const float* cur = zA;
  for (int s = 1; s < NSTEPS; ++s) {
    float* dst = (s == NSTEPS - 1) ? out : ((s & 1) ? zB : zA);
    fused_step<<<grid, block, 0, stream>>>(cur, dst, W1, b1, W2, b2);
    cur = dst;
  }
}

// Round 8
// 1163.871 us; speedup vs baseline: 8.9162x; 8.9162x over previous
//
#include <hip/hip_runtime.h>
#include <hip/hip_bf16.h>

// Problem constants (reference: t1_t0=1, TOL=0.05 -> 20 SSP-RK3 steps)
#define MB     32
#define NCH    4
#define LL     2048
#define HID    64
#define KSZ    5
#define GG     10
#define RI     (LL - 2*GG)   // 2028
#define TPOS   128
#define NTILES 16
#define THR    256
#define NSTEPS 20
#define HSTEP  0.05f

__device__ __forceinline__ int pmap(int q) {
  // bdry read map: ghost -> interior source (period RI)
  if (q < GG) return q + RI;
  if (q >= LL - GG) return q - RI;
  return q;
}

// ======================= proven round-2 per-stage kernel =======================
template<bool MAP, bool SCATTER>
__global__ __launch_bounds__(THR, 2)
void stage_kernel(const float* __restrict__ z, const float* __restrict__ cin,
                  float* __restrict__ outp,
                  const float* __restrict__ W1g, const float* __restrict__ b1g,
                  const float* __restrict__ W2g, const float* __restrict__ b2g,
                  float ca, float cb, float cc_)
{
  __shared__ float in_s[NCH][TPOS + 8];
  __shared__ __align__(16) float th_s[TPOS + 4][HID];
  __shared__ __align__(16) float w2s[NCH][KSZ][HID];
  __shared__ float b2s[NCH];

  const int t    = threadIdx.x;
  const int tile = blockIdx.x;
  const int mi   = blockIdx.y;
  const int p0 = GG + tile * TPOS;
  const int validT = min(TPOS, (LL - GG) - p0);

  for (int i = t; i < NCH * KSZ * HID; i += THR) {
    int co = i / (KSZ * HID); int rem = i - co * (KSZ * HID);
    int k = rem / HID; int c2 = rem - k * HID;
    w2s[co][k][c2] = W2g[(co * HID + c2) * KSZ + k];
  }
  if (t < NCH) b2s[t] = b2g[t];
  const int c = t & 63;
  float w1r[NCH * KSZ];
  #pragma unroll
  for (int i = 0; i < NCH * KSZ; ++i) w1r[i] = W1g[c * (NCH * KSZ) + i];
  const float b1r = b1g[c];

  const float* zb   = z   + mi * (NCH * LL);
  const float* cinb = cin + mi * (NCH * LL);
  float*       outb = outp + mi * (NCH * LL);

  const int LOADN = validT + 8;
  for (int i = t; i < NCH * (TPOS + 8); i += THR) {
    int ci = i / (TPOS + 8);
    int j  = i - ci * (TPOS + 8);
    if (j < LOADN) {
      int q  = p0 - 4 + j;
      int qq = MAP ? pmap(q) : q;
      in_s[ci][j] = cinb[ci * LL + qq];
    }
  }
  __syncthreads();

  {
    const int pg = t >> 6;
    const int THN = validT + 4;
    const int j0  = pg * 35;
    const int j1  = min(THN, j0 + 35);
    float zw[NCH][KSZ];
    #pragma unroll
    for (int d = 0; d < 4; ++d) {
      #pragma unroll
      for (int ci = 0; ci < NCH; ++ci)
        zw[ci][d] = in_s[ci][j0 + d];
    }
    for (int jb = j0; jb < j1; jb += 5) {
      #pragma unroll
      for (int u = 0; u < 5; ++u) {
        int j = jb + u;
        if (j < j1) {
          #pragma unroll
          for (int ci = 0; ci < NCH; ++ci)
            zw[ci][(u + 4) % 5] = in_s[ci][j + 4];
          float acc = b1r;
          #pragma unroll
          for (int ci = 0; ci < NCH; ++ci) {
            #pragma unroll
            for (int k = 0; k < KSZ; ++k)
              acc = fmaf(w1r[ci * KSZ + k], zw[ci][(u + k) % 5], acc);
          }
          float e  = __expf(2.0f * acc);
          float th = 1.0f - 2.0f * __frcp_rn(e + 1.0f);
          th_s[j][(((c >> 2) ^ (j & 15)) << 2) | (c & 3)] = th;
        }
      }
    }
  }
  __syncthreads();

  {
    const int x   = t >> 1;
    const int cop = t & 1;
    if (x < validT) {
      const int co0 = cop * 2, co1 = co0 + 1;
      float a0 = b2s[co0], a1 = b2s[co1];
      const float4* w2v0 = (const float4*)&w2s[co0][0][0];
      const float4* w2v1 = (const float4*)&w2s[co1][0][0];
      #pragma unroll
      for (int k = 0; k < KSZ; ++k) {
        const int row = x + k;
        const float4* thv = (const float4*)&th_s[row][0];
        const int rs = row & 15;
        #pragma unroll
        for (int ccn = 0; ccn < 16; ++ccn) {
          float4 tv = thv[ccn ^ rs];
          float4 wa = w2v0[k * 16 + ccn];
          float4 wb = w2v1[k * 16 + ccn];
          a0 = fmaf(tv.x, wa.x, a0); a0 = fmaf(tv.y, wa.y, a0);
          a0 = fmaf(tv.z, wa.z, a0); a0 = fmaf(tv.w, wa.w, a0);
          a1 = fmaf(tv.x, wb.x, a1); a1 = fmaf(tv.y, wb.y, a1);
          a1 = fmaf(tv.z, wb.z, a1); a1 = fmaf(tv.w, wb.w, a1);
        }
      }
      const int p = p0 + x;
      float v0 = ca * zb[co0 * LL + p] + cb * cinb[co0 * LL + p] + cc_ * a0;
      float v1 = ca * zb[co1 * LL + p] + cb * cinb[co1 * LL + p] + cc_ * a1;
      outb[co0 * LL + p] = v0;
      outb[co1 * LL + p] = v1;
      if (SCATTER) {
        if (p >= LL - 2 * GG && p < LL - GG) {
          outb[co0 * LL + p - RI] = v0;
          outb[co1 * LL + p - RI] = v1;
        }
        if (p >= GG && p < 2 * GG) {
          outb[co0 * LL + p + RI] = v0;
          outb[co1 * LL + p + RI] = v1;
        }
      }
    }
  }
}

// ======================= fused full-step kernel (steps >= 2) ====================
// FLAT version: no helper functions, no LDS pointers through parameters.
// All LDS accesses are on the named __shared__ arrays (stage_kernel's proven
// textual patterns), so the compiler sees addrspace(3) directly.
//
// Index maps (verified by passing r6/r7):
//   in_sv[j]  = z  at ext pos j-12, j in [0, validT+24)
//   th pass A: th_s[j] = tanh(conv1(z))  centered j-10, j in [0, validT+20)
//   u1_sv[i]  = u1 at ext pos i-8,  i in [0, validT+16)   rows i..i+4, z=in_sv[i+4]
//   th pass B: th_s[j] = tanh(conv1(u1)) centered j-6,  j in [0, validT+12)
//   u2_sv[i]  = u2 at ext pos i-4,  i in [0, validT+8)    rows i..i+4, z=in_sv[i+8], u1=u1_sv[i+4]
//   th pass C: th_s[j] = tanh(conv1(u2)) centered j-2,  j in [0, validT+4)
//   out[x], x in [0, validT): rows x..x+4, z=in_sv[x+12], u2=u2_sv[x+4]

#define RUN_CONV1(SRC, R)                                                      \
  {                                                                            \
    const int RP = ((R) + 3) >> 2;                                             \
    const int j0 = pg * RP;                                                    \
    const int j1 = min((R), j0 + RP);                                          \
    for (int j = j0; j < j1; ++j) {                                            \
      float acc = b1r;                                                         \
      _Pragma("unroll")                                                        \
      for (int k = 0; k < KSZ; ++k) {                                          \
        float4 pk = SRC[j + k];                                                \
        acc = fmaf(w1r[0 * KSZ + k], pk.x, acc);                               \
        acc = fmaf(w1r[1 * KSZ + k], pk.y, acc);                               \
        acc = fmaf(w1r[2 * KSZ + k], pk.z, acc);                               \
        acc = fmaf(w1r[3 * KSZ + k], pk.w, acc);                               \
      }                                                                        \
      float e  = __expf(2.0f * acc);                                           \
      float th = 1.0f - 2.0f * __frcp_rn(e + 1.0f);                            \
      th_s[j][(((c >> 2) ^ (j & 15)) << 2) | (c & 3)] = th;                    \
    }                                                                          \
  }

#define CONV2_AT(X, A0, A1)                                                    \
  {                                                                            \
    _Pragma("unroll")                                                          \
    for (int k = 0; k < KSZ; ++k) {                                            \
      const int row = (X) + k;                                                 \
      const int rs  = row & 15;                                                \
      _Pragma("unroll")                                                        \
      for (int ccn = 0; ccn < 16; ++ccn) {                                     \
        const float4 tv = *(const float4*)&th_s[row][(ccn ^ rs) << 2];         \
        const float4 wa = *(const float4*)&w2s[co0][k][ccn << 2];              \
        const float4 wb = *(const float4*)&w2s[co1][k][ccn << 2];              \
        A0 = fmaf(tv.x, wa.x, A0); A0 = fmaf(tv.y, wa.y, A0);                  \
        A0 = fmaf(tv.z, wa.z, A0); A0 = fmaf(tv.w, wa.w, A0);                  \
        A1 = fmaf(tv.x, wb.x, A1); A1 = fmaf(tv.y, wb.y, A1);                  \
        A1 = fmaf(tv.z, wb.z, A1); A1 = fmaf(tv.w, wb.w, A1);                  \
      }                                                                        \
    }                                                                          \
  }

__global__ __launch_bounds__(THR, 2)
void fused_step(const float* __restrict__ zin, float* __restrict__ zout,
                const float* __restrict__ W1g, const float* __restrict__ b1g,
                const float* __restrict__ W2g, const float* __restrict__ b2g)
{
  __shared__ float4 in_sv[TPOS + 24];                   // z ext [-12, T+12)
  __shared__ __align__(16) float th_s[TPOS + 20][HID];  // swizzled hidden tile
  __shared__ float4 u1_sv[TPOS + 16];                   // u1 ext [-8, T+8)
  __shared__ float4 u2_sv[TPOS + 8];                    // u2 ext [-4, T+4)
  __shared__ __align__(16) float w2s[NCH][KSZ][HID];
  __shared__ float b2s[NCH];

  const int t    = threadIdx.x;
  const int tile = blockIdx.x;
  const int mi   = blockIdx.y;
  const int r0   = tile * TPOS;                         // ring coord of tile start
  const int validT = min(TPOS, RI - r0);

  for (int i = t; i < NCH * KSZ * HID; i += THR) {
    int co = i / (KSZ * HID); int rem = i - co * (KSZ * HID);
    int k = rem / HID; int c2 = rem - k * HID;
    w2s[co][k][c2] = W2g[(co * HID + c2) * KSZ + k];
  }
  if (t < NCH) b2s[t] = b2g[t];
  const int c  = t & 63;
  const int pg = t >> 6;
  const int cop = t & 1;
  const int co0 = cop * 2, co1 = co0 + 1;
  float w1r[NCH * KSZ];
  #pragma unroll
  for (int i = 0; i < NCH * KSZ; ++i) w1r[i] = W1g[c * (NCH * KSZ) + i];
  const float b1r = b1g[c];

  const float h = HSTEP;
  const float* zb = zin  + (size_t)mi * NCH * LL;
  float*     outb = zout + (size_t)mi * NCH * LL;

  // load z ext tile (interior reads only; ring wrap == bdry for steps >= 2)
  for (int j = t; j < validT + 24; j += THR) {
    int q = r0 + j - 12; if (q < 0) q += RI; if (q >= RI) q -= RI;
    int lp = q + GG;
    in_sv[j] = make_float4(zb[0 * LL + lp], zb[1 * LL + lp],
                           zb[2 * LL + lp], zb[3 * LL + lp]);
  }
  __syncthreads();

  // ---- stage 1: u1 = z + h f(z) on ext [-8, T+8) ----
  RUN_CONV1(in_sv, validT + 20);
  __syncthreads();
  #pragma unroll
  for (int rep = 0; rep < 2; ++rep) {
    const int x = (t >> 1) + rep * 128;
    if (x < validT + 16) {
      float a0 = b2s[co0], a1 = b2s[co1];
      CONV2_AT(x, a0, a1);
      const float* zp = (const float*)&in_sv[x + 4];
      float* op = (float*)&u1_sv[x];
      op[co0] = zp[co0] + h * a0;
      op[co1] = zp[co1] + h * a1;
    }
  }
  __syncthreads();

  // ---- stage 2: u2 = 0.75 z + 0.25 u1 + 0.25 h f(u1) on ext [-4, T+4) ----
  RUN_CONV1(u1_sv, validT + 12);
  __syncthreads();
  #pragma unroll
  for (int rep = 0; rep < 2; ++rep) {
    const int x = (t >> 1) + rep * 128;
    if (x < validT + 8) {
      float a0 = b2s[co0], a1 = b2s[co1];
      CONV2_AT(x, a0, a1);
      const float* zp = (const float*)&in_sv[x + 8];
      const float* cp = (const float*)&u1_sv[x + 4];
      float* op = (float*)&u2_sv[x];
      op[co0] = 0.75f * zp[co0] + 0.25f * cp[co0] + 0.25f * h * a0;
      op[co1] = 0.75f * zp[co1] + 0.25f * cp[co1] + 0.25f * h * a1;
    }
  }
  __syncthreads();

  // ---- stage 3: z' = z/3 + 2/3 u2 + (2h/3) f(u2) on [0, T) -> global line ----
  RUN_CONV1(u2_sv, validT + 4);
  __syncthreads();
  {
    const int x = t >> 1;
    if (x < validT) {
      float a0 = b2s[co0], a1 = b2s[co1];
      CONV2_AT(x, a0, a1);
      const float* zp = (const float*)&in_sv[x + 12];
      const float* cp = (const float*)&u2_sv[x + 4];
      float v0 = (1.0f / 3.0f) * zp[co0] + (2.0f / 3.0f) * cp[co0] + (2.0f * h / 3.0f) * a0;
      float v1 = (1.0f / 3.0f) * zp[co1] + (2.0f / 3.0f) * cp[co1] + (2.0f * h / 3.0f) * a1;
      const int p = r0 + GG + x;
      outb[co0 * LL + p] = v0;
      outb[co1 * LL + p] = v1;
      if (p >= LL - 2 * GG && p < LL - GG) {   // -> low ghosts [0,G)
        outb[co0 * LL + p - RI] = v0;
        outb[co1 * LL + p - RI] = v1;
      }
      if (p >= GG && p < 2 * GG) {             // -> high ghosts [L-G,L)
        outb[co0 * LL + p + RI] = v0;
        outb[co1 * LL + p + RI] = v1;
      }
    }
  }
}

extern "C" void kernel_launch(void* const* d_in, const int* in_sizes, int n_in,
                              void* d_out, int out_size, void* d_ws, size_t ws_size,
                              hipStream_t stream) {
  const float* z0 = (const float*)d_in[0];
  const float* W1 = (const float*)d_in[1];
  const float* b1 = (const float*)d_in[2];
  const float* W2 = (const float*)d_in[3];
  const float* b2 = (const float*)d_in[4];
  float* out = (float*)d_out;

  const size_t ELEMS = (size_t)MB * NCH * LL;
  float* zA  = (float*)d_ws;
  float* zB  = zA + ELEMS;
  float* u1p = zB + ELEMS;
  float* u2p = u1p + ELEMS;

  const float h = HSTEP;
  dim3 grid(NTILES, MB);
  dim3 block(THR);

  // ---- step 1: per-stage (z0's raw ghosts are semantically meaningful) ----
  stage_kernel<false, false><<<grid, block, 0, stream>>>(
      z0, z0, u1p, W1, b1, W2, b2, 1.0f, 0.0f, h);
  stage_kernel<true, false><<<grid, block, 0, stream>>>(
      z0, u1p, u2p, W1, b1, W2, b2, 0.75f, 0.25f, 0.25f * h);
  stage_kernel<true, true><<<grid, block, 0, stream>>>(
      z0, u2p, zA, W1, b1, W2, b2, 1.0f / 3.0f, 2.0f / 3.0f, 2.0f * h / 3.0f);

  // ---- steps 2..20: one fused launch per step ----
  const float* cur = zA;
  for (int s = 1; s < NSTEPS; ++s) {
    float* dst = (s == NSTEPS - 1) ? out : ((s & 1) ? zB : zA);
    fused_step<<<grid, block, 0, stream>>>(cur, dst, W1, b1, W2, b2);
    cur = dst;
  }
}